// Round 1
// baseline (180.570 us; speedup 1.0000x reference)
//
#include <hip/hip_runtime.h>

// Problem constants (SubOut_60206851555968): B=8, U=E=1024, D=P=256, fp32 in/out.
#define BDIM 8
#define UDIM 1024
#define EDIM 1024
#define DDIM 256
#define PDIM 256

typedef __attribute__((ext_vector_type(8))) short bf16x8;   // 8 bf16 = 4 VGPRs
typedef __attribute__((ext_vector_type(4))) float f32x4;

__device__ __forceinline__ short f2bf(float x) {
    unsigned u = __float_as_uint(x);
    unsigned r = (u + 0x7FFFu + ((u >> 16) & 1u)) >> 16;   // RNE
    return (short)r;
}

// ---------------------------------------------------------------------------
// prep: wT[n][k] = bf16(w[k][n]); zero sums + out.
// v2: 64 blocks; each thread reads a float4 of w (4 n-cols for its k) and
// writes 4 coalesced ushort rows of wT. 64*256 = 16384 threads = sums size.
// ---------------------------------------------------------------------------
__global__ __launch_bounds__(256) void prep_kernel(
    const float* __restrict__ w, ushort* __restrict__ wT,
    float* __restrict__ sums /* row_sums||col_sums, 16384 */,
    float* __restrict__ out, int out_size)
{
    int k  = threadIdx.x;          // D index
    int n0 = blockIdx.x * 4;       // P index base
    float4 wv = *(const float4*)(w + (size_t)k * PDIM + n0);
    wT[(size_t)(n0 + 0) * DDIM + k] = (ushort)f2bf(wv.x);
    wT[(size_t)(n0 + 1) * DDIM + k] = (ushort)f2bf(wv.y);
    wT[(size_t)(n0 + 2) * DDIM + k] = (ushort)f2bf(wv.z);
    wT[(size_t)(n0 + 3) * DDIM + k] = (ushort)f2bf(wv.w);
    int g = blockIdx.x * 256 + k;
    sums[g] = 0.f;                              // exactly 16384
    if (g < out_size) out[g] = 0.f;
}

// ---------------------------------------------------------------------------
// proj: u_p/e_p = bf16(enc @ w + bias), MFMA 16x16x32 bf16.
// v2: (a) all 16 A-float4s batch-loaded into registers first (MLP 16 instead
// of 2 — the kernel was latency-bound, not BW-bound); (b) 1-D grid with XCD
// swizzle so the 4 col-blocks sharing an A row-strip run on the SAME XCD
// (A fetched ~1x from HBM instead of 4x).
// ---------------------------------------------------------------------------
__global__ __launch_bounds__(256) void proj_kernel(
    const float* __restrict__ u_enc, const float* __restrict__ e_enc,
    const ushort* __restrict__ wT, const float* __restrict__ bias,
    ushort* __restrict__ u_p, ushort* __restrict__ e_p)
{
    // bid&7 -> XCD (round-robin dispatch); within an XCD, consecutive lin
    // walks col-blocks fastest so A-strip reuse is temporal + same-L2.
    int bid  = blockIdx.x;                 // 0..1023
    int lin  = (bid & 7) * 128 + (bid >> 3);
    int row0 = (lin >> 2) * 64;
    int col0 = (lin & 3) * 64;

    const float* A; ushort* C;
    if (row0 < BDIM * UDIM) { A = u_enc; C = u_p; }
    else                    { A = e_enc; C = e_p; row0 -= BDIM * UDIM; }

    int tid  = threadIdx.x;
    int wave = tid >> 6, lane = tid & 63;
    int m = lane & 15, quad = lane >> 4;

    const float* aptr = A + (size_t)(row0 + wave * 16 + m) * DDIM + quad * 8;

    // Batch all A loads: 16 float4 = 64 VGPR in flight, one latency hit.
    float4 a[16];
    #pragma unroll
    for (int i = 0; i < 8; ++i) {
        a[2 * i]     = *(const float4*)(aptr + 32 * i);
        a[2 * i + 1] = *(const float4*)(aptr + 32 * i + 4);
    }

    f32x4 acc[4] = {};
    #pragma unroll
    for (int i = 0; i < 8; ++i) {
        bf16x8 af;
        af[0] = f2bf(a[2*i].x);   af[1] = f2bf(a[2*i].y);
        af[2] = f2bf(a[2*i].z);   af[3] = f2bf(a[2*i].w);
        af[4] = f2bf(a[2*i+1].x); af[5] = f2bf(a[2*i+1].y);
        af[6] = f2bf(a[2*i+1].z); af[7] = f2bf(a[2*i+1].w);
        int k0 = 32 * i;
        #pragma unroll
        for (int nt = 0; nt < 4; ++nt) {
            bf16x8 bfr = *(const bf16x8*)(wT + (size_t)(col0 + nt * 16 + m) * DDIM + k0 + quad * 8);
            acc[nt] = __builtin_amdgcn_mfma_f32_16x16x32_bf16(af, bfr, acc[nt], 0, 0, 0);
        }
    }

    // C/D layout: col = lane&15, row = quad*4 + reg.
    #pragma unroll
    for (int nt = 0; nt < 4; ++nt) {
        int col = col0 + nt * 16 + m;
        float bv = bias[col];
        #pragma unroll
        for (int r = 0; r < 4; ++r) {
            int row = row0 + wave * 16 + quad * 4 + r;
            C[(size_t)row * PDIM + col] = (ushort)f2bf(acc[nt][r] + bv);
        }
    }
}

// ---------------------------------------------------------------------------
// fused: op = u_p . e_p (MFMA), gate, row/col reduction. mask never hits HBM.
// v3 (latency attack — counters showed MfmaUtil 3% / VALU 11% / HBM 14%,
// i.e. pure latency-bound with MLP ~2-4 at VGPR=48):
//   * af frags for all 8 K-steps batch-loaded up front (32 VGPR).
//   * pm/mm epilogue loads batched into register arrays AFTER the MFMAs
//     (issuing them earlier would make every later frag-load wait on the
//     in-order vmcnt FIFO behind 900-cy HBM returns). sched_barrier(0)
//     fences keep the scheduler from sinking them into the compute.
//   * 1-D grid, b = bid&7: each batch's u_p/e_p (2+2 MB) pins to one XCD L2.
// ---------------------------------------------------------------------------
__global__ __launch_bounds__(256) void fused_kernel(
    const ushort* __restrict__ u_p, const ushort* __restrict__ e_p,
    const float* __restrict__ pair_enc, const float* __restrict__ ue_mask,
    const float* __restrict__ bpp_w_p, const float* __restrict__ bpp_b_p,
    float* __restrict__ row_sums, float* __restrict__ col_sums)
{
    __shared__ float colred[4][64];

    int bid  = blockIdx.x;          // 0..2047
    int b    = bid & 7;             // batch <-> XCD
    int tile = bid >> 3;            // 0..255
    int iu = tile >> 4, ie = tile & 15;
    int u0 = iu * 64, e0 = ie * 64;

    int tid  = threadIdx.x;
    int wave = tid >> 6, lane = tid & 63;
    int m = lane & 15, quad = lane >> 4;

    const ushort* Au = u_p + (size_t)b * UDIM * PDIM + (size_t)(u0 + wave * 16 + m) * PDIM + quad * 8;
    const ushort* Be = e_p + (size_t)b * EDIM * PDIM + (size_t)(e0 + m) * PDIM + quad * 8;

    // Batch all A-frags (u_p strip slice for this lane): 8 x 16B in flight.
    bf16x8 af[8];
    #pragma unroll
    for (int i = 0; i < 8; ++i) af[i] = *(const bf16x8*)(Au + 32 * i);

    float bw = bpp_w_p[0], bb = bpp_b_p[0];

    f32x4 acc[4] = {};
    #pragma unroll
    for (int i = 0; i < 8; ++i) {
        #pragma unroll
        for (int nt = 0; nt < 4; ++nt) {
            bf16x8 bfr = *(const bf16x8*)(Be + (size_t)nt * 16 * PDIM + 32 * i);
            acc[nt] = __builtin_amdgcn_mfma_f32_16x16x32_bf16(af[i], bfr, acc[nt], 0, 0, 0);
        }
    }

    const float* pm = pair_enc + (size_t)b * UDIM * EDIM;
    const float* mm = ue_mask  + (size_t)b * UDIM * EDIM;

    // --- batched epilogue loads: 32 dwords in flight, one latency hit ---
    __builtin_amdgcn_sched_barrier(0);   // don't hoist these above the MFMAs
    float mvv[16], pvv[16];
    #pragma unroll
    for (int r = 0; r < 4; ++r) {
        size_t rowoff = (size_t)(u0 + wave * 16 + quad * 4 + r) * EDIM + e0 + m;
        #pragma unroll
        for (int nt = 0; nt < 4; ++nt) {
            mvv[r * 4 + nt] = mm[rowoff + nt * 16];
            pvv[r * 4 + nt] = pm[rowoff + nt * 16];
        }
    }
    __builtin_amdgcn_sched_barrier(0);   // issue ALL loads before any compute

    // Epilogue: gate + partial sums. C layout: row = quad*4+reg, col = lane&15 (+16*nt).
    float rsum[4] = {0.f, 0.f, 0.f, 0.f};
    float csum[4] = {0.f, 0.f, 0.f, 0.f};
    #pragma unroll
    for (int r = 0; r < 4; ++r) {
        #pragma unroll
        for (int nt = 0; nt < 4; ++nt) {
            float mv = mvv[r * 4 + nt], pv = pvv[r * 4 + nt];
            float arg = bw * pv + bb + mv * acc[nt][r];
            float s = mv / (1.f + __expf(-arg));
            rsum[r]  += s;
            csum[nt] += s;
        }
    }

    // Row sums: reduce across the 16 lanes of each quad (cols). Row is unique
    // to (wave, quad, r) -> direct atomicAdd from the quad leader.
    #pragma unroll
    for (int r = 0; r < 4; ++r) {
        float v = rsum[r];
        v += __shfl_xor(v, 1); v += __shfl_xor(v, 2);
        v += __shfl_xor(v, 4); v += __shfl_xor(v, 8);
        if (m == 0)
            atomicAdd(&row_sums[(size_t)b * UDIM + u0 + wave * 16 + quad * 4 + r], v);
    }

    // Col sums: reduce across quads (rows within strip), then across waves via LDS.
    #pragma unroll
    for (int nt = 0; nt < 4; ++nt) {
        float v = csum[nt];
        v += __shfl_xor(v, 16); v += __shfl_xor(v, 32);
        if (quad == 0) colred[wave][nt * 16 + m] = v;
    }
    __syncthreads();

    if (tid < 64) {
        float v = colred[0][tid] + colred[1][tid] + colred[2][tid] + colred[3][tid];
        atomicAdd(&col_sums[(size_t)b * EDIM + e0 + tid], v);
    }
}

// ---------------------------------------------------------------------------
// finish: out[b,0:256] = row_sums[b,:] @ u_enc[b]; out[b,256:512] = col_sums @ e_enc.
// v2: 64 chunks of 16 (1024 blocks = 4/CU instead of 1/CU) and the 16 enc
// loads batched into registers (MLP 16). s[] loads are block-uniform ->
// scalar loads. fp32 throughout; atomicAdd into zeroed out.
// ---------------------------------------------------------------------------
__global__ __launch_bounds__(256) void finish_kernel(
    const float* __restrict__ u_enc, const float* __restrict__ e_enc,
    const float* __restrict__ row_sums, const float* __restrict__ col_sums,
    float* __restrict__ out)
{
    int b = blockIdx.x;
    int half = blockIdx.y;
    int chunk = blockIdx.z;        // 0..63
    int d = threadIdx.x;

    const float* enc = half ? e_enc : u_enc;
    const float* s   = half ? col_sums : row_sums;

    int base = chunk * 16;
    float ev[16];
    #pragma unroll
    for (int j = 0; j < 16; ++j)
        ev[j] = enc[(size_t)(b * UDIM + base + j) * DDIM + d];

    float acc = 0.f;
    #pragma unroll
    for (int j = 0; j < 16; ++j)
        acc += s[(size_t)b * UDIM + base + j] * ev[j];

    atomicAdd(&out[(size_t)b * 2 * DDIM + half * DDIM + d], acc);
}

// ---------------------------------------------------------------------------
extern "C" void kernel_launch(void* const* d_in, const int* in_sizes, int n_in,
                              void* d_out, int out_size, void* d_ws, size_t ws_size,
                              hipStream_t stream)
{
    const float* u_enc    = (const float*)d_in[0];
    const float* e_enc    = (const float*)d_in[1];
    const float* pair_enc = (const float*)d_in[2];
    const float* ue_mask  = (const float*)d_in[3];
    const float* w_kernel = (const float*)d_in[4];
    const float* w_bias   = (const float*)d_in[5];
    const float* bpp_w    = (const float*)d_in[6];
    const float* bpp_b    = (const float*)d_in[7];
    float* out = (float*)d_out;

    // ws layout: u_p bf16 (4MB) | e_p bf16 (4MB) | wT bf16 (128KB) | sums fp32 (64KB)
    ushort* u_p = (ushort*)d_ws;
    ushort* e_p = u_p + (size_t)BDIM * UDIM * PDIM;
    ushort* wT  = e_p + (size_t)BDIM * EDIM * PDIM;
    float* row_sums = (float*)(wT + (size_t)DDIM * PDIM);
    float* col_sums = row_sums + BDIM * UDIM;

    prep_kernel<<<dim3(64), 256, 0, stream>>>(w_kernel, wT, row_sums, out, out_size);

    proj_kernel<<<dim3(1024), 256, 0, stream>>>(u_enc, e_enc, wT, w_bias, u_p, e_p);

    fused_kernel<<<dim3(2048), 256, 0, stream>>>(u_p, e_p, pair_enc, ue_mask,
                                                 bpp_w, bpp_b, row_sums, col_sums);

    finish_kernel<<<dim3(BDIM, 2, 64), 256, 0, stream>>>(u_enc, e_enc, row_sums, col_sums, out);
}